// Round 5
// baseline (4260.179 us; speedup 1.0000x reference)
//
#include <hip/hip_runtime.h>
#include <hip/hip_bf16.h>
#include <math.h>

#define NTOK 4096   // B*S = 8*512
#define HD   768
#define FD   3072
#define NE   6
#define TM   16     // tokens per ffn block
#define FC   64     // F-chunk width

__device__ __forceinline__ float gelu_exact(float v) {
    return 0.5f * v * (1.f + erff(v * 0.70710678118654752f));
}

// One wave per token: gate scores, top-2, softmax, bias-init of out, routing lists.
__global__ __launch_bounds__(64)
void gate_kernel(const float* __restrict__ x, const float* __restrict__ gw,
                 const float* __restrict__ gb, const float* __restrict__ b2,
                 float* __restrict__ out, int* __restrict__ cnt,
                 int* __restrict__ tlist, float* __restrict__ wlist)
{
    const int n = blockIdx.x;
    const int lane = threadIdx.x;
    const float* xr = x + (size_t)n * HD;

    float p[NE] = {0.f, 0.f, 0.f, 0.f, 0.f, 0.f};
    for (int hh = lane; hh < HD; hh += 64) {
        const float xv = xr[hh];
        const float* g = gw + (size_t)hh * NE;
        #pragma unroll
        for (int e = 0; e < NE; ++e) p[e] = fmaf(xv, g[e], p[e]);
    }
    #pragma unroll
    for (int off = 32; off; off >>= 1) {
        #pragma unroll
        for (int e = 0; e < NE; ++e) p[e] += __shfl_xor(p[e], off, 64);
    }
    #pragma unroll
    for (int e = 0; e < NE; ++e) p[e] += gb[e];

    // top-2 (ties -> lowest index, matching lax.top_k)
    int e0 = 0; float s0 = p[0];
    #pragma unroll
    for (int e = 1; e < NE; ++e) if (p[e] > s0) { s0 = p[e]; e0 = e; }
    int e1 = -1; float s1 = -INFINITY;
    #pragma unroll
    for (int e = 0; e < NE; ++e) if (e != e0 && p[e] > s1) { s1 = p[e]; e1 = e; }

    const float ev = expf(s1 - s0);          // s0 >= s1
    const float w0 = 1.f / (1.f + ev);
    const float w1 = ev / (1.f + ev);

    // init out with weighted b2 (so FFN kernel only atomically adds matmul parts)
    const float* bp0 = b2 + (size_t)e0 * HD;
    const float* bp1 = b2 + (size_t)e1 * HD;
    float* orow = out + (size_t)n * HD;
    for (int hh = lane; hh < HD; hh += 64)
        orow[hh] = fmaf(w0, bp0[hh], w1 * bp1[hh]);

    if (lane == 0) {
        int q0 = atomicAdd(&cnt[e0], 1);
        tlist[e0 * NTOK + q0] = n; wlist[e0 * NTOK + q0] = w0;
        int q1 = atomicAdd(&cnt[e1], 1);
        tlist[e1 * NTOK + q1] = n; wlist[e1 * NTOK + q1] = w1;
    }
}

// Fused expert FFN: block = (expert, tile of <=16 tokens).
// GEMM1: Hs[f][m] = gelu(X @ w1 + b1) per 64-wide F chunk.
// GEMM2: acc[16][768] (in regs, 48/thread) += Hs @ w2 chunk.
// Epilogue: weighted atomicAdd into out.
__global__ __launch_bounds__(256)
void ffn_kernel(const float* __restrict__ x, const float* __restrict__ w1,
                const float* __restrict__ b1, const float* __restrict__ w2,
                float* __restrict__ out, const int* __restrict__ cnt,
                const int* __restrict__ tlist, const float* __restrict__ wlist)
{
    const int e = blockIdx.y;
    const int ce = cnt[e];
    const int row0 = blockIdx.x * TM;
    if (row0 >= ce) return;
    const int nrows = min(TM, ce - row0);

    __shared__ float Xs[TM][HD];       // 48 KB
    __shared__ float Hs[FC][20];       // 5 KB (pad 20: 8-way-max write conflicts; 80B stride keeps float4 reads 16B-aligned)
    __shared__ int   toks[TM];
    __shared__ float wgts[TM];

    const int tid = threadIdx.x;
    if (tid < TM) {
        const int idx = row0 + min(tid, nrows - 1);   // clamp padding rows
        toks[tid] = tlist[e * NTOK + idx];
        wgts[tid] = (tid < nrows) ? wlist[e * NTOK + row0 + tid] : 0.f;
    }
    __syncthreads();

    // stage X tile (16 rows x 768, float4, coalesced per row)
    for (int i = tid; i < TM * (HD / 4); i += 256) {
        const int m = i / (HD / 4), c = i % (HD / 4);
        ((float4*)&Xs[m][0])[c] = ((const float4*)(x + (size_t)toks[m] * HD))[c];
    }
    __syncthreads();

    float acc[TM * 3];
    #pragma unroll
    for (int i = 0; i < TM * 3; ++i) acc[i] = 0.f;

    const float* w1e = w1 + (size_t)e * HD * FD;
    const float* w2e = w2 + (size_t)e * FD * HD;
    const float* b1e = b1 + (size_t)e * FD;

    const int fl0 = (tid & 15) * 4;   // 4 consecutive f per thread (float4 w1 loads)
    const int mg  = tid >> 4;         // token row for GEMM1 (0..15)

    for (int f0 = 0; f0 < FD; f0 += FC) {
        // ---- GEMM1: d[j] = dot(X[mg], w1[:, f0+fl0+j]) ----
        float d0 = 0.f, d1 = 0.f, d2 = 0.f, d3 = 0.f;
        const float* wc = w1e + f0 + fl0;
        for (int hh = 0; hh < HD; hh += 4) {
            const float4 xv = *(const float4*)&Xs[mg][hh];
            const float4 a0 = *(const float4*)(wc + (size_t)(hh + 0) * FD);
            const float4 a1 = *(const float4*)(wc + (size_t)(hh + 1) * FD);
            const float4 a2 = *(const float4*)(wc + (size_t)(hh + 2) * FD);
            const float4 a3 = *(const float4*)(wc + (size_t)(hh + 3) * FD);
            d0 = fmaf(xv.x, a0.x, d0); d0 = fmaf(xv.y, a1.x, d0);
            d0 = fmaf(xv.z, a2.x, d0); d0 = fmaf(xv.w, a3.x, d0);
            d1 = fmaf(xv.x, a0.y, d1); d1 = fmaf(xv.y, a1.y, d1);
            d1 = fmaf(xv.z, a2.y, d1); d1 = fmaf(xv.w, a3.y, d1);
            d2 = fmaf(xv.x, a0.z, d2); d2 = fmaf(xv.y, a1.z, d2);
            d2 = fmaf(xv.z, a2.z, d2); d2 = fmaf(xv.w, a3.z, d2);
            d3 = fmaf(xv.x, a0.w, d3); d3 = fmaf(xv.y, a1.w, d3);
            d3 = fmaf(xv.z, a2.w, d3); d3 = fmaf(xv.w, a3.w, d3);
        }
        // bias + exact GeLU, store transposed Hs[f][m]
        Hs[fl0 + 0][mg] = gelu_exact(d0 + b1e[f0 + fl0 + 0]);
        Hs[fl0 + 1][mg] = gelu_exact(d1 + b1e[f0 + fl0 + 1]);
        Hs[fl0 + 2][mg] = gelu_exact(d2 + b1e[f0 + fl0 + 2]);
        Hs[fl0 + 3][mg] = gelu_exact(d3 + b1e[f0 + fl0 + 3]);
        __syncthreads();

        // ---- GEMM2: acc[m][h] += Hs[f][m] * w2[f0+f][h], h = tid + 256c ----
        for (int f = 0; f < FC; ++f) {
            const float* wr = w2e + (size_t)(f0 + f) * HD;
            const float wa = wr[tid], wb = wr[tid + 256], wcv = wr[tid + 512];
            // 4x float4 uniform-address (broadcast) LDS reads of Hs[f][0..15]
            #pragma unroll
            for (int q = 0; q < 4; ++q) {
                const float4 hv = *(const float4*)&Hs[f][q * 4];
                acc[(q * 4 + 0) * 3 + 0] = fmaf(hv.x, wa,  acc[(q * 4 + 0) * 3 + 0]);
                acc[(q * 4 + 0) * 3 + 1] = fmaf(hv.x, wb,  acc[(q * 4 + 0) * 3 + 1]);
                acc[(q * 4 + 0) * 3 + 2] = fmaf(hv.x, wcv, acc[(q * 4 + 0) * 3 + 2]);
                acc[(q * 4 + 1) * 3 + 0] = fmaf(hv.y, wa,  acc[(q * 4 + 1) * 3 + 0]);
                acc[(q * 4 + 1) * 3 + 1] = fmaf(hv.y, wb,  acc[(q * 4 + 1) * 3 + 1]);
                acc[(q * 4 + 1) * 3 + 2] = fmaf(hv.y, wcv, acc[(q * 4 + 1) * 3 + 2]);
                acc[(q * 4 + 2) * 3 + 0] = fmaf(hv.z, wa,  acc[(q * 4 + 2) * 3 + 0]);
                acc[(q * 4 + 2) * 3 + 1] = fmaf(hv.z, wb,  acc[(q * 4 + 2) * 3 + 1]);
                acc[(q * 4 + 2) * 3 + 2] = fmaf(hv.z, wcv, acc[(q * 4 + 2) * 3 + 2]);
                acc[(q * 4 + 3) * 3 + 0] = fmaf(hv.w, wa,  acc[(q * 4 + 3) * 3 + 0]);
                acc[(q * 4 + 3) * 3 + 1] = fmaf(hv.w, wb,  acc[(q * 4 + 3) * 3 + 1]);
                acc[(q * 4 + 3) * 3 + 2] = fmaf(hv.w, wcv, acc[(q * 4 + 3) * 3 + 2]);
            }
        }
        __syncthreads();   // Hs rewritten next iteration
    }

    // ---- epilogue: weighted atomic accumulate (each token hit by exactly 2 expert blocks) ----
    #pragma unroll
    for (int m = 0; m < TM; ++m) {
        if (m < nrows) {
            const float wg = wgts[m];
            float* orow = out + (size_t)toks[m] * HD;
            atomicAdd(&orow[tid],        wg * acc[m * 3 + 0]);
            atomicAdd(&orow[tid + 256],  wg * acc[m * 3 + 1]);
            atomicAdd(&orow[tid + 512],  wg * acc[m * 3 + 2]);
        }
    }
}

extern "C" void kernel_launch(void* const* d_in, const int* in_sizes, int n_in,
                              void* d_out, int out_size, void* d_ws, size_t ws_size,
                              hipStream_t stream) {
    const float* x  = (const float*)d_in[0];
    const float* gw = (const float*)d_in[1];
    const float* gb = (const float*)d_in[2];
    const float* w1 = (const float*)d_in[3];
    const float* b1 = (const float*)d_in[4];
    const float* w2 = (const float*)d_in[5];
    const float* b2 = (const float*)d_in[6];
    float* out = (float*)d_out;

    char* ws = (char*)d_ws;
    int*   cnt   = (int*)ws;                                  // 6 ints (zeroed below)
    int*   tlist = (int*)(ws + 64);                           // [E][NTOK]
    float* wlist = (float*)(ws + 64 + (size_t)NE * NTOK * 4); // [E][NTOK]

    hipMemsetAsync(cnt, 0, 64, stream);
    gate_kernel<<<NTOK, 64, 0, stream>>>(x, gw, gb, b2, out, cnt, tlist, wlist);
    ffn_kernel<<<dim3(NTOK / TM, NE), 256, 0, stream>>>(x, w1, b1, w2, out, cnt, tlist, wlist);
}

// Round 6
// 3736.595 us; speedup vs baseline: 1.1401x; 1.1401x over previous
//
#include <hip/hip_runtime.h>
#include <hip/hip_bf16.h>
#include <math.h>

#define NTOK 4096   // B*S = 8*512
#define HD   768
#define FD   3072
#define NE   6
#define TM   8      // tokens per ffn block (was 16: LDS 54.8->33.5 KB, 2->4 blocks/CU)
#define FC   128    // F-chunk width (24 chunks)

__device__ __forceinline__ float gelu_exact(float v) {
    return 0.5f * v * (1.f + erff(v * 0.70710678118654752f));
}

// One wave per token: gate scores, top-2, softmax, bias-init of out, routing lists.
__global__ __launch_bounds__(64)
void gate_kernel(const float* __restrict__ x, const float* __restrict__ gw,
                 const float* __restrict__ gb, const float* __restrict__ b2,
                 float* __restrict__ out, int* __restrict__ cnt,
                 int* __restrict__ tlist, float* __restrict__ wlist)
{
    const int n = blockIdx.x;
    const int lane = threadIdx.x;
    const float* xr = x + (size_t)n * HD;

    float p[NE] = {0.f, 0.f, 0.f, 0.f, 0.f, 0.f};
    for (int hh = lane; hh < HD; hh += 64) {
        const float xv = xr[hh];
        const float* g = gw + (size_t)hh * NE;
        #pragma unroll
        for (int e = 0; e < NE; ++e) p[e] = fmaf(xv, g[e], p[e]);
    }
    #pragma unroll
    for (int off = 32; off; off >>= 1) {
        #pragma unroll
        for (int e = 0; e < NE; ++e) p[e] += __shfl_xor(p[e], off, 64);
    }
    #pragma unroll
    for (int e = 0; e < NE; ++e) p[e] += gb[e];

    // top-2 (ties -> lowest index, matching lax.top_k)
    int e0 = 0; float s0 = p[0];
    #pragma unroll
    for (int e = 1; e < NE; ++e) if (p[e] > s0) { s0 = p[e]; e0 = e; }
    int e1 = -1; float s1 = -INFINITY;
    #pragma unroll
    for (int e = 0; e < NE; ++e) if (e != e0 && p[e] > s1) { s1 = p[e]; e1 = e; }

    const float ev = expf(s1 - s0);          // s0 >= s1
    const float w0 = 1.f / (1.f + ev);
    const float w1 = ev / (1.f + ev);

    // init out with weighted b2 (so FFN kernel only atomically adds matmul parts)
    const float* bp0 = b2 + (size_t)e0 * HD;
    const float* bp1 = b2 + (size_t)e1 * HD;
    float* orow = out + (size_t)n * HD;
    for (int hh = lane; hh < HD; hh += 64)
        orow[hh] = fmaf(w0, bp0[hh], w1 * bp1[hh]);

    if (lane == 0) {
        int q0 = atomicAdd(&cnt[e0], 1);
        tlist[e0 * NTOK + q0] = n; wlist[e0 * NTOK + q0] = w0;
        int q1 = atomicAdd(&cnt[e1], 1);
        tlist[e1 * NTOK + q1] = n; wlist[e1 * NTOK + q1] = w1;
    }
}

// Fused expert FFN: block = (expert, tile of <=8 tokens), 256 threads.
// GEMM1: thread (mg=tid>>5, fc0=(tid&31)*4) computes 4 f-cols of its row.
// Hs double-buffered [2][TM][FC+4]: 1 barrier/chunk. GEMM2 Hs reads are
// wave-uniform broadcasts (conflict-free). Xs padded +4 -> mg rows on
// disjoint banks (conflict-free GEMM1 reads).
__global__ __launch_bounds__(256, 4)
void ffn_kernel(const float* __restrict__ x, const float* __restrict__ w1,
                const float* __restrict__ b1, const float* __restrict__ w2,
                float* __restrict__ out, const int* __restrict__ cnt,
                const int* __restrict__ tlist, const float* __restrict__ wlist)
{
    const int e = blockIdx.y;
    const int ce = cnt[e];
    const int row0 = blockIdx.x * TM;
    if (row0 >= ce) return;
    const int nrows = min(TM, ce - row0);

    __shared__ float Xs[TM][HD + 4];     // 24.7 KB, stride 772 (772%32=4 -> bank-spread rows)
    __shared__ float Hs[2][TM][FC + 4];  // 8.4 KB, stride 132 floats (528 B, 16B-aligned)
    __shared__ int   toks[TM];
    __shared__ float wgts[TM];

    const int tid = threadIdx.x;
    if (tid < TM) {
        const int idx = row0 + min(tid, nrows - 1);   // clamp padding rows
        toks[tid] = tlist[e * NTOK + idx];
        wgts[tid] = (tid < nrows) ? wlist[e * NTOK + row0 + tid] : 0.f;
    }
    __syncthreads();

    // stage X tile (8 rows x 768, float4, coalesced per row)
    for (int i = tid; i < TM * (HD / 4); i += 256) {
        const int m = i / (HD / 4), c = i % (HD / 4);
        ((float4*)&Xs[m][0])[c] = ((const float4*)(x + (size_t)toks[m] * HD))[c];
    }

    float acc[TM * 3];
    #pragma unroll
    for (int i = 0; i < TM * 3; ++i) acc[i] = 0.f;

    const float* w1e = w1 + (size_t)e * HD * FD;
    const float* w2e = w2 + (size_t)e * FD * HD;
    const float* b1e = b1 + (size_t)e * FD;

    const int fc0 = (tid & 31) * 4;   // 4 consecutive f per thread (float4 w1 loads)
    const int mg  = tid >> 5;         // token row for GEMM1 (0..7)

    __syncthreads();                  // Xs ready

    for (int c = 0; c < FD / FC; ++c) {
        const int f0 = c * FC;
        const int buf = c & 1;

        // ---- GEMM1: d[j] = dot(X[mg], w1[:, f0+fc0+j]) ----
        float d0 = 0.f, d1 = 0.f, d2 = 0.f, d3 = 0.f;
        const float* wc = w1e + f0 + fc0;
        #pragma unroll 2
        for (int hh = 0; hh < HD; hh += 4) {
            const float4 xv = *(const float4*)&Xs[mg][hh];
            const float4 a0 = *(const float4*)(wc + (size_t)(hh + 0) * FD);
            const float4 a1 = *(const float4*)(wc + (size_t)(hh + 1) * FD);
            const float4 a2 = *(const float4*)(wc + (size_t)(hh + 2) * FD);
            const float4 a3 = *(const float4*)(wc + (size_t)(hh + 3) * FD);
            d0 = fmaf(xv.x, a0.x, d0); d0 = fmaf(xv.y, a1.x, d0);
            d0 = fmaf(xv.z, a2.x, d0); d0 = fmaf(xv.w, a3.x, d0);
            d1 = fmaf(xv.x, a0.y, d1); d1 = fmaf(xv.y, a1.y, d1);
            d1 = fmaf(xv.z, a2.y, d1); d1 = fmaf(xv.w, a3.y, d1);
            d2 = fmaf(xv.x, a0.z, d2); d2 = fmaf(xv.y, a1.z, d2);
            d2 = fmaf(xv.z, a2.z, d2); d2 = fmaf(xv.w, a3.z, d2);
            d3 = fmaf(xv.x, a0.w, d3); d3 = fmaf(xv.y, a1.w, d3);
            d3 = fmaf(xv.z, a2.w, d3); d3 = fmaf(xv.w, a3.w, d3);
        }
        // bias + exact GeLU, one float4 write into double-buffered Hs[mg][fc0..+3]
        const float4 bv = *(const float4*)&b1e[f0 + fc0];
        float4 hv;
        hv.x = gelu_exact(d0 + bv.x);
        hv.y = gelu_exact(d1 + bv.y);
        hv.z = gelu_exact(d2 + bv.z);
        hv.w = gelu_exact(d3 + bv.w);
        *(float4*)&Hs[buf][mg][fc0] = hv;
        __syncthreads();   // only barrier per chunk: Hs[buf] complete.
        // (GEMM1 of chunk c+1 writes Hs[buf^1]; Hs[buf] is safe to reuse only
        //  after the NEXT barrier, by which time all waves finished this GEMM2.)

        // ---- GEMM2: acc[m][h] += Hs[m][f] * w2[f0+f][h], h = tid + 256k ----
        for (int f = 0; f < FC; f += 4) {
            const float4 h0 = *(const float4*)&Hs[buf][0][f];
            const float4 h1 = *(const float4*)&Hs[buf][1][f];
            const float4 h2 = *(const float4*)&Hs[buf][2][f];
            const float4 h3 = *(const float4*)&Hs[buf][3][f];
            const float4 h4 = *(const float4*)&Hs[buf][4][f];
            const float4 h5 = *(const float4*)&Hs[buf][5][f];
            const float4 h6 = *(const float4*)&Hs[buf][6][f];
            const float4 h7 = *(const float4*)&Hs[buf][7][f];
            #pragma unroll
            for (int j = 0; j < 4; ++j) {
                const float* wr = w2e + (size_t)(f0 + f + j) * HD + tid;
                const float wa = wr[0], wb = wr[256], wcv = wr[512];
                const float m0 = ((const float*)&h0)[j];
                const float m1 = ((const float*)&h1)[j];
                const float m2 = ((const float*)&h2)[j];
                const float m3 = ((const float*)&h3)[j];
                const float m4 = ((const float*)&h4)[j];
                const float m5 = ((const float*)&h5)[j];
                const float m6 = ((const float*)&h6)[j];
                const float m7 = ((const float*)&h7)[j];
                acc[0*3+0] = fmaf(m0, wa, acc[0*3+0]); acc[0*3+1] = fmaf(m0, wb, acc[0*3+1]); acc[0*3+2] = fmaf(m0, wcv, acc[0*3+2]);
                acc[1*3+0] = fmaf(m1, wa, acc[1*3+0]); acc[1*3+1] = fmaf(m1, wb, acc[1*3+1]); acc[1*3+2] = fmaf(m1, wcv, acc[1*3+2]);
                acc[2*3+0] = fmaf(m2, wa, acc[2*3+0]); acc[2*3+1] = fmaf(m2, wb, acc[2*3+1]); acc[2*3+2] = fmaf(m2, wcv, acc[2*3+2]);
                acc[3*3+0] = fmaf(m3, wa, acc[3*3+0]); acc[3*3+1] = fmaf(m3, wb, acc[3*3+1]); acc[3*3+2] = fmaf(m3, wcv, acc[3*3+2]);
                acc[4*3+0] = fmaf(m4, wa, acc[4*3+0]); acc[4*3+1] = fmaf(m4, wb, acc[4*3+1]); acc[4*3+2] = fmaf(m4, wcv, acc[4*3+2]);
                acc[5*3+0] = fmaf(m5, wa, acc[5*3+0]); acc[5*3+1] = fmaf(m5, wb, acc[5*3+1]); acc[5*3+2] = fmaf(m5, wcv, acc[5*3+2]);
                acc[6*3+0] = fmaf(m6, wa, acc[6*3+0]); acc[6*3+1] = fmaf(m6, wb, acc[6*3+1]); acc[6*3+2] = fmaf(m6, wcv, acc[6*3+2]);
                acc[7*3+0] = fmaf(m7, wa, acc[7*3+0]); acc[7*3+1] = fmaf(m7, wb, acc[7*3+1]); acc[7*3+2] = fmaf(m7, wcv, acc[7*3+2]);
            }
        }
    }

    // ---- epilogue: weighted atomic accumulate (each token hit by exactly 2 expert blocks) ----
    #pragma unroll
    for (int m = 0; m < TM; ++m) {
        if (m < nrows) {
            const float wg = wgts[m];
            float* orow = out + (size_t)toks[m] * HD;
            atomicAdd(&orow[tid],        wg * acc[m * 3 + 0]);
            atomicAdd(&orow[tid + 256],  wg * acc[m * 3 + 1]);
            atomicAdd(&orow[tid + 512],  wg * acc[m * 3 + 2]);
        }
    }
}

extern "C" void kernel_launch(void* const* d_in, const int* in_sizes, int n_in,
                              void* d_out, int out_size, void* d_ws, size_t ws_size,
                              hipStream_t stream) {
    const float* x  = (const float*)d_in[0];
    const float* gw = (const float*)d_in[1];
    const float* gb = (const float*)d_in[2];
    const float* w1 = (const float*)d_in[3];
    const float* b1 = (const float*)d_in[4];
    const float* w2 = (const float*)d_in[5];
    const float* b2 = (const float*)d_in[6];
    float* out = (float*)d_out;

    char* ws = (char*)d_ws;
    int*   cnt   = (int*)ws;                                  // 6 ints (zeroed below)
    int*   tlist = (int*)(ws + 64);                           // [E][NTOK]
    float* wlist = (float*)(ws + 64 + (size_t)NE * NTOK * 4); // [E][NTOK]

    hipMemsetAsync(cnt, 0, 64, stream);
    gate_kernel<<<NTOK, 64, 0, stream>>>(x, gw, gb, b2, out, cnt, tlist, wlist);
    ffn_kernel<<<dim3(NTOK / TM, NE), 256, 0, stream>>>(x, w1, b1, w2, out, cnt, tlist, wlist);
}

// Round 7
// 1445.015 us; speedup vs baseline: 2.9482x; 2.5859x over previous
//
#include <hip/hip_runtime.h>
#include <hip/hip_bf16.h>
#include <math.h>

#define NTOK 4096   // B*S
#define HD   768
#define FD   3072
#define NE   6

// ---------- vector-path (fallback) tile params ----------
#define TM   8
#define FC   128
// ---------- mfma-path params ----------
#define MT   64     // tokens per block
#define NSH  2      // F shards
#define FSH  (FD / NSH)   // 1536
#define FCH  128    // F chunk

typedef __attribute__((ext_vector_type(8))) short short8;
typedef __attribute__((ext_vector_type(4))) float f32x4;
#define MFMA_BF16(a, b, c) __builtin_amdgcn_mfma_f32_16x16x32_bf16(a, b, c, 0, 0, 0)

__device__ __forceinline__ float gelu_exact(float v) {
    return 0.5f * v * (1.f + erff(v * 0.70710678118654752f));
}

__device__ __forceinline__ void split_bf16(float v, short& hi, short& lo) {
    __hip_bfloat16 h = __float2bfloat16(v);
    hi = *reinterpret_cast<short*>(&h);
    float fh = __bfloat162float(h);
    __hip_bfloat16 l = __float2bfloat16(v - fh);
    lo = *reinterpret_cast<short*>(&l);
}

// ================= gating =================
__global__ __launch_bounds__(64)
void gate_kernel(const float* __restrict__ x, const float* __restrict__ gw,
                 const float* __restrict__ gb, const float* __restrict__ b2,
                 float* __restrict__ out, int* __restrict__ cnt,
                 int* __restrict__ tlist, float* __restrict__ wlist)
{
    const int n = blockIdx.x;
    const int lane = threadIdx.x;
    const float* xr = x + (size_t)n * HD;

    float p[NE] = {0.f, 0.f, 0.f, 0.f, 0.f, 0.f};
    for (int hh = lane; hh < HD; hh += 64) {
        const float xv = xr[hh];
        const float* g = gw + (size_t)hh * NE;
        #pragma unroll
        for (int e = 0; e < NE; ++e) p[e] = fmaf(xv, g[e], p[e]);
    }
    #pragma unroll
    for (int off = 32; off; off >>= 1) {
        #pragma unroll
        for (int e = 0; e < NE; ++e) p[e] += __shfl_xor(p[e], off, 64);
    }
    #pragma unroll
    for (int e = 0; e < NE; ++e) p[e] += gb[e];

    int e0 = 0; float s0 = p[0];
    #pragma unroll
    for (int e = 1; e < NE; ++e) if (p[e] > s0) { s0 = p[e]; e0 = e; }
    int e1 = -1; float s1 = -INFINITY;
    #pragma unroll
    for (int e = 0; e < NE; ++e) if (e != e0 && p[e] > s1) { s1 = p[e]; e1 = e; }

    const float ev = expf(s1 - s0);
    const float w0 = 1.f / (1.f + ev);
    const float w1 = ev / (1.f + ev);

    const float* bp0 = b2 + (size_t)e0 * HD;
    const float* bp1 = b2 + (size_t)e1 * HD;
    float* orow = out + (size_t)n * HD;
    for (int hh = lane; hh < HD; hh += 64)
        orow[hh] = fmaf(w0, bp0[hh], w1 * bp1[hh]);

    if (lane == 0) {
        int q0 = atomicAdd(&cnt[e0], 1);
        tlist[e0 * NTOK + q0] = n; wlist[e0 * NTOK + q0] = w0;
        int q1 = atomicAdd(&cnt[e1], 1);
        tlist[e1 * NTOK + q1] = n; wlist[e1 * NTOK + q1] = w1;
    }
}

// ================= prep: split x into bf16 hi/lo =================
__global__ __launch_bounds__(256)
void split_x_kernel(const float* __restrict__ x, short* __restrict__ xh, short* __restrict__ xl)
{
    const int N = NTOK * HD;
    for (int i = blockIdx.x * 256 + threadIdx.x; i < N; i += gridDim.x * 256) {
        short h, l; split_bf16(x[i], h, l);
        xh[i] = h; xl[i] = l;
    }
}

// ================= prep: pack w1 -> [e][k/8][f][8] bf16 hi/lo =================
// thread = (e, kg, f); reads 8 rows coalesced over f; writes 16B/thread contiguous.
__global__ __launch_bounds__(256)
void pack_w1_kernel(const float* __restrict__ w1, short* __restrict__ w1ph, short* __restrict__ w1pl)
{
    const int N = NE * (HD / 8) * FD;
    for (int i = blockIdx.x * 256 + threadIdx.x; i < N; i += gridDim.x * 256) {
        const int f  = i % FD;
        const int kg = (i / FD) % (HD / 8);
        const int e  = i / (FD * (HD / 8));
        const float* src = w1 + (size_t)e * HD * FD + (size_t)kg * 8 * FD + f;
        short hs[8], ls[8];
        #pragma unroll
        for (int j = 0; j < 8; ++j) split_bf16(src[(size_t)j * FD], hs[j], ls[j]);
        const size_t d = (size_t)i * 8;
        *(short8*)(w1ph + d) = *(short8*)hs;
        *(short8*)(w1pl + d) = *(short8*)ls;
    }
}

// ================= prep: pack w2 -> [e][f/8][h][8] bf16 hi/lo =================
__global__ __launch_bounds__(256)
void pack_w2_kernel(const float* __restrict__ w2, short* __restrict__ w2ph, short* __restrict__ w2pl)
{
    const int N = NE * (FD / 8) * HD;
    for (int i = blockIdx.x * 256 + threadIdx.x; i < N; i += gridDim.x * 256) {
        const int h  = i % HD;
        const int fg = (i / HD) % (FD / 8);
        const int e  = i / (HD * (FD / 8));
        const float* src = w2 + (size_t)e * FD * HD + (size_t)fg * 8 * HD + h;
        short hs[8], ls[8];
        #pragma unroll
        for (int j = 0; j < 8; ++j) split_bf16(src[(size_t)j * HD], hs[j], ls[j]);
        const size_t d = (size_t)i * 8;
        *(short8*)(w2ph + d) = *(short8*)hs;
        *(short8*)(w2pl + d) = *(short8*)ls;
    }
}

// ================= MFMA fused FFN =================
// Block = (token-tile of 64, F-shard of 1536, expert). 512 threads = 8 waves (2 row x 4 col groups).
// GEMM1 per 128-F chunk: C1[64][128] via mfma_16x16x32_bf16 3-term split; bias+GeLU -> Hs (LDS, bf16 hi/lo).
// GEMM2: acc[64][768] held in registers across chunks (24 frags/wave); epilogue: weighted atomicAdd.
__global__ __launch_bounds__(512, 2)
void ffn_mfma(const short* __restrict__ xh, const short* __restrict__ xl,
              const short* __restrict__ w1ph, const short* __restrict__ w1pl,
              const short* __restrict__ w2ph, const short* __restrict__ w2pl,
              const float* __restrict__ b1, float* __restrict__ out,
              const int* __restrict__ cnt, const int* __restrict__ tlist,
              const float* __restrict__ wlist)
{
    const int e = blockIdx.z;
    const int s = blockIdx.y;
    const int ce = cnt[e];
    const int row0 = blockIdx.x * MT;
    if (row0 >= ce) return;
    const int nrows = min(MT, ce - row0);

    __shared__ __align__(16) short Hs_h[MT][FCH + 8];
    __shared__ __align__(16) short Hs_l[MT][FCH + 8];
    __shared__ int   toks[MT];
    __shared__ float wgts[MT];

    const int tid = threadIdx.x;
    if (tid < MT) {
        toks[tid] = tlist[e * NTOK + row0 + min(tid, nrows - 1)];
        wgts[tid] = (tid < nrows) ? wlist[e * NTOK + row0 + tid] : 0.f;
    }
    __syncthreads();

    const int lane = tid & 63;
    const int wave = tid >> 6;        // 0..7
    const int l15  = lane & 15;
    const int lk   = lane >> 4;       // 0..3
    const int wr   = wave >> 2;       // 0..1 : rows wr*32 + [0,32)
    const int wc   = wave & 3;        // 0..3 : gemm1 cols wc*32, gemm2 cols wc*192

    const int rA0 = wr * 32 + l15;        // token row for rt=0 A-frags
    const int rA1 = wr * 32 + 16 + l15;   // rt=1
    const size_t tok0 = (size_t)toks[rA0] * HD;
    const size_t tok1 = (size_t)toks[rA1] * HD;

    f32x4 acc2[2][12];
    #pragma unroll
    for (int a = 0; a < 2; ++a)
        #pragma unroll
        for (int b = 0; b < 12; ++b) acc2[a][b] = (f32x4)(0.f);

    const float* b1e = b1 + (size_t)e * FD;

    for (int ch = 0; ch < FSH / FCH; ++ch) {
        const int fbase = s * FSH + ch * FCH;

        // ---------- GEMM1: C1[64][128] ----------
        f32x4 acc1[2][2];
        #pragma unroll
        for (int a = 0; a < 2; ++a) { acc1[a][0] = (f32x4)(0.f); acc1[a][1] = (f32x4)(0.f); }

        const int fcol0 = fbase + wc * 32 + l15;        // ct=0 column
        #pragma unroll 4
        for (int ks = 0; ks < HD / 32; ++ks) {          // 24 K-steps of 32
            const int k0 = ks * 32 + lk * 8;
            const short8 ah0 = *(const short8*)(xh + tok0 + k0);
            const short8 al0 = *(const short8*)(xl + tok0 + k0);
            const short8 ah1 = *(const short8*)(xh + tok1 + k0);
            const short8 al1 = *(const short8*)(xl + tok1 + k0);
            const size_t bro = ((size_t)(e * (HD / 8) + ks * 4 + lk) * FD);
            const short8 bh0 = *(const short8*)(w1ph + (bro + fcol0) * 8);
            const short8 bl0 = *(const short8*)(w1pl + (bro + fcol0) * 8);
            const short8 bh1 = *(const short8*)(w1ph + (bro + fcol0 + 16) * 8);
            const short8 bl1 = *(const short8*)(w1pl + (bro + fcol0 + 16) * 8);
            acc1[0][0] = MFMA_BF16(ah0, bh0, acc1[0][0]);
            acc1[0][0] = MFMA_BF16(al0, bh0, acc1[0][0]);
            acc1[0][0] = MFMA_BF16(ah0, bl0, acc1[0][0]);
            acc1[0][1] = MFMA_BF16(ah0, bh1, acc1[0][1]);
            acc1[0][1] = MFMA_BF16(al0, bh1, acc1[0][1]);
            acc1[0][1] = MFMA_BF16(ah0, bl1, acc1[0][1]);
            acc1[1][0] = MFMA_BF16(ah1, bh0, acc1[1][0]);
            acc1[1][0] = MFMA_BF16(al1, bh0, acc1[1][0]);
            acc1[1][0] = MFMA_BF16(ah1, bl0, acc1[1][0]);
            acc1[1][1] = MFMA_BF16(ah1, bh1, acc1[1][1]);
            acc1[1][1] = MFMA_BF16(al1, bh1, acc1[1][1]);
            acc1[1][1] = MFMA_BF16(ah1, bl1, acc1[1][1]);
        }

        // bias + GeLU + split -> Hs
        #pragma unroll
        for (int ct = 0; ct < 2; ++ct) {
            const int flocal = wc * 32 + ct * 16 + l15;
            const float bias = b1e[fbase + flocal];
            #pragma unroll
            for (int rt = 0; rt < 2; ++rt) {
                #pragma unroll
                for (int j = 0; j < 4; ++j) {
                    const float v = gelu_exact(acc1[rt][ct][j] + bias);
                    short h, l; split_bf16(v, h, l);
                    const int r = wr * 32 + rt * 16 + lk * 4 + j;   // C/D: row=(lane>>4)*4+reg
                    Hs_h[r][flocal] = h;
                    Hs_l[r][flocal] = l;
                }
            }
        }
        __syncthreads();

        // ---------- GEMM2: acc2 += H[64][128] @ w2[128][768-slice] ----------
        #pragma unroll
        for (int ks = 0; ks < FCH / 32; ++ks) {          // 4 K-steps
            const int k0 = ks * 32 + lk * 8;             // local f
            const short8 ah0 = *(const short8*)&Hs_h[wr * 32 + l15][k0];
            const short8 al0 = *(const short8*)&Hs_l[wr * 32 + l15][k0];
            const short8 ah1 = *(const short8*)&Hs_h[wr * 32 + 16 + l15][k0];
            const short8 al1 = *(const short8*)&Hs_l[wr * 32 + 16 + l15][k0];
            const size_t bro = (size_t)(e * (FD / 8) + ((fbase + ks * 32) >> 3) + lk) * HD;
            #pragma unroll
            for (int ct = 0; ct < 12; ++ct) {
                const int h = wc * 192 + ct * 16 + l15;
                const short8 bh = *(const short8*)(w2ph + (bro + h) * 8);
                const short8 bl = *(const short8*)(w2pl + (bro + h) * 8);
                acc2[0][ct] = MFMA_BF16(ah0, bh, acc2[0][ct]);
                acc2[0][ct] = MFMA_BF16(al0, bh, acc2[0][ct]);
                acc2[0][ct] = MFMA_BF16(ah0, bl, acc2[0][ct]);
                acc2[1][ct] = MFMA_BF16(ah1, bh, acc2[1][ct]);
                acc2[1][ct] = MFMA_BF16(al1, bh, acc2[1][ct]);
                acc2[1][ct] = MFMA_BF16(ah1, bl, acc2[1][ct]);
            }
        }
        __syncthreads();   // Hs rewritten next chunk
    }

    // ---------- epilogue ----------
    #pragma unroll
    for (int rt = 0; rt < 2; ++rt) {
        #pragma unroll
        for (int j = 0; j < 4; ++j) {
            const int r = wr * 32 + rt * 16 + lk * 4 + j;
            if (r < nrows) {
                const float wg = wgts[r];
                float* orow = out + (size_t)toks[r] * HD;
                #pragma unroll
                for (int ct = 0; ct < 12; ++ct)
                    atomicAdd(&orow[wc * 192 + ct * 16 + l15], wg * acc2[rt][ct][j]);
            }
        }
    }
}

// ================= vector fallback FFN (round-6 kernel) =================
__global__ __launch_bounds__(256, 4)
void ffn_kernel(const float* __restrict__ x, const float* __restrict__ w1,
                const float* __restrict__ b1, const float* __restrict__ w2,
                float* __restrict__ out, const int* __restrict__ cnt,
                const int* __restrict__ tlist, const float* __restrict__ wlist)
{
    const int e = blockIdx.y;
    const int ce = cnt[e];
    const int row0 = blockIdx.x * TM;
    if (row0 >= ce) return;
    const int nrows = min(TM, ce - row0);

    __shared__ float Xs[TM][HD + 4];
    __shared__ float Hs[2][TM][FC + 4];
    __shared__ int   toks[TM];
    __shared__ float wgts[TM];

    const int tid = threadIdx.x;
    if (tid < TM) {
        const int idx = row0 + min(tid, nrows - 1);
        toks[tid] = tlist[e * NTOK + idx];
        wgts[tid] = (tid < nrows) ? wlist[e * NTOK + row0 + tid] : 0.f;
    }
    __syncthreads();

    for (int i = tid; i < TM * (HD / 4); i += 256) {
        const int m = i / (HD / 4), c = i % (HD / 4);
        ((float4*)&Xs[m][0])[c] = ((const float4*)(x + (size_t)toks[m] * HD))[c];
    }

    float acc[TM * 3];
    #pragma unroll
    for (int i = 0; i < TM * 3; ++i) acc[i] = 0.f;

    const float* w1e = w1 + (size_t)e * HD * FD;
    const float* w2e = w2 + (size_t)e * FD * HD;
    const float* b1e = b1 + (size_t)e * FD;

    const int fc0 = (tid & 31) * 4;
    const int mg  = tid >> 5;

    __syncthreads();

    for (int c = 0; c < FD / FC; ++c) {
        const int f0 = c * FC;
        const int buf = c & 1;
        float d0 = 0.f, d1 = 0.f, d2 = 0.f, d3 = 0.f;
        const float* wcp = w1e + f0 + fc0;
        #pragma unroll 2
        for (int hh = 0; hh < HD; hh += 4) {
            const float4 xv = *(const float4*)&Xs[mg][hh];
            const float4 a0 = *(const float4*)(wcp + (size_t)(hh + 0) * FD);
            const float4 a1 = *(const float4*)(wcp + (size_t)(hh + 1) * FD);
            const float4 a2 = *(const float4*)(wcp + (size_t)(hh + 2) * FD);
            const float4 a3 = *(const float4*)(wcp + (size_t)(hh + 3) * FD);
            d0 = fmaf(xv.x, a0.x, d0); d0 = fmaf(xv.y, a1.x, d0);
            d0 = fmaf(xv.z, a2.x, d0); d0 = fmaf(xv.w, a3.x, d0);
            d1 = fmaf(xv.x, a0.y, d1); d1 = fmaf(xv.y, a1.y, d1);
            d1 = fmaf(xv.z, a2.y, d1); d1 = fmaf(xv.w, a3.y, d1);
            d2 = fmaf(xv.x, a0.z, d2); d2 = fmaf(xv.y, a1.z, d2);
            d2 = fmaf(xv.z, a2.z, d2); d2 = fmaf(xv.w, a3.z, d2);
            d3 = fmaf(xv.x, a0.w, d3); d3 = fmaf(xv.y, a1.w, d3);
            d3 = fmaf(xv.z, a2.w, d3); d3 = fmaf(xv.w, a3.w, d3);
        }
        const float4 bv = *(const float4*)&b1e[f0 + fc0];
        float4 hv;
        hv.x = gelu_exact(d0 + bv.x);
        hv.y = gelu_exact(d1 + bv.y);
        hv.z = gelu_exact(d2 + bv.z);
        hv.w = gelu_exact(d3 + bv.w);
        *(float4*)&Hs[buf][mg][fc0] = hv;
        __syncthreads();

        for (int f = 0; f < FC; f += 4) {
            const float4 h0 = *(const float4*)&Hs[buf][0][f];
            const float4 h1 = *(const float4*)&Hs[buf][1][f];
            const float4 h2 = *(const float4*)&Hs[buf][2][f];
            const float4 h3 = *(const float4*)&Hs[buf][3][f];
            const float4 h4 = *(const float4*)&Hs[buf][4][f];
            const float4 h5 = *(const float4*)&Hs[buf][5][f];
            const float4 h6 = *(const float4*)&Hs[buf][6][f];
            const float4 h7 = *(const float4*)&Hs[buf][7][f];
            #pragma unroll
            for (int j = 0; j < 4; ++j) {
                const float* wr = w2e + (size_t)(f0 + f + j) * HD + tid;
                const float wa = wr[0], wb = wr[256], wcv = wr[512];
                const float m0 = ((const float*)&h0)[j];
                const float m1 = ((const float*)&h1)[j];
                const float m2 = ((const float*)&h2)[j];
                const float m3 = ((const float*)&h3)[j];
                const float m4 = ((const float*)&h4)[j];
                const float m5 = ((const float*)&h5)[j];
                const float m6 = ((const float*)&h6)[j];
                const float m7 = ((const float*)&h7)[j];
                acc[0*3+0] = fmaf(m0, wa, acc[0*3+0]); acc[0*3+1] = fmaf(m0, wb, acc[0*3+1]); acc[0*3+2] = fmaf(m0, wcv, acc[0*3+2]);
                acc[1*3+0] = fmaf(m1, wa, acc[1*3+0]); acc[1*3+1] = fmaf(m1, wb, acc[1*3+1]); acc[1*3+2] = fmaf(m1, wcv, acc[1*3+2]);
                acc[2*3+0] = fmaf(m2, wa, acc[2*3+0]); acc[2*3+1] = fmaf(m2, wb, acc[2*3+1]); acc[2*3+2] = fmaf(m2, wcv, acc[2*3+2]);
                acc[3*3+0] = fmaf(m3, wa, acc[3*3+0]); acc[3*3+1] = fmaf(m3, wb, acc[3*3+1]); acc[3*3+2] = fmaf(m3, wcv, acc[3*3+2]);
                acc[4*3+0] = fmaf(m4, wa, acc[4*3+0]); acc[4*3+1] = fmaf(m4, wb, acc[4*3+1]); acc[4*3+2] = fmaf(m4, wcv, acc[4*3+2]);
                acc[5*3+0] = fmaf(m5, wa, acc[5*3+0]); acc[5*3+1] = fmaf(m5, wb, acc[5*3+1]); acc[5*3+2] = fmaf(m5, wcv, acc[5*3+2]);
                acc[6*3+0] = fmaf(m6, wa, acc[6*3+0]); acc[6*3+1] = fmaf(m6, wb, acc[6*3+1]); acc[6*3+2] = fmaf(m6, wcv, acc[6*3+2]);
                acc[7*3+0] = fmaf(m7, wa, acc[7*3+0]); acc[7*3+1] = fmaf(m7, wb, acc[7*3+1]); acc[7*3+2] = fmaf(m7, wcv, acc[7*3+2]);
            }
        }
    }

    #pragma unroll
    for (int m = 0; m < TM; ++m) {
        if (m < nrows) {
            const float wg = wgts[m];
            float* orow = out + (size_t)toks[m] * HD;
            atomicAdd(&orow[tid],        wg * acc[m * 3 + 0]);
            atomicAdd(&orow[tid + 256],  wg * acc[m * 3 + 1]);
            atomicAdd(&orow[tid + 512],  wg * acc[m * 3 + 2]);
        }
    }
}

extern "C" void kernel_launch(void* const* d_in, const int* in_sizes, int n_in,
                              void* d_out, int out_size, void* d_ws, size_t ws_size,
                              hipStream_t stream) {
    const float* x  = (const float*)d_in[0];
    const float* gw = (const float*)d_in[1];
    const float* gb = (const float*)d_in[2];
    const float* w1 = (const float*)d_in[3];
    const float* b1 = (const float*)d_in[4];
    const float* w2 = (const float*)d_in[5];
    const float* b2 = (const float*)d_in[6];
    float* out = (float*)d_out;

    char* ws = (char*)d_ws;
    int*   cnt   = (int*)ws;
    int*   tlist = (int*)(ws + 64);
    float* wlist = (float*)(ws + 64 + (size_t)NE * NTOK * 4);

    const size_t base   = 196864;                 // 256-aligned end of lists
    const size_t sz_x   = (size_t)NTOK * HD * 2;  // bf16
    const size_t sz_w1  = (size_t)NE * HD * FD * 2;
    const size_t sz_w2  = (size_t)NE * FD * HD * 2;
    const size_t REQ    = base + 2 * sz_x + 2 * sz_w1 + 2 * sz_w2;

    hipMemsetAsync(cnt, 0, 64, stream);
    gate_kernel<<<NTOK, 64, 0, stream>>>(x, gw, gb, b2, out, cnt, tlist, wlist);

    if (ws_size >= REQ) {
        short* xh   = (short*)(ws + base);
        short* xl   = (short*)(ws + base + sz_x);
        short* w1ph = (short*)(ws + base + 2 * sz_x);
        short* w1pl = (short*)(ws + base + 2 * sz_x + sz_w1);
        short* w2ph = (short*)(ws + base + 2 * sz_x + 2 * sz_w1);
        short* w2pl = (short*)(ws + base + 2 * sz_x + 2 * sz_w1 + sz_w2);

        split_x_kernel<<<2048, 256, 0, stream>>>(x, xh, xl);
        pack_w1_kernel<<<2048, 256, 0, stream>>>(w1, w1ph, w1pl);
        pack_w2_kernel<<<2048, 256, 0, stream>>>(w2, w2ph, w2pl);
        ffn_mfma<<<dim3(NTOK / MT, NSH, NE), 512, 0, stream>>>(
            xh, xl, w1ph, w1pl, w2ph, w2pl, b1, out, cnt, tlist, wlist);
    } else {
        ffn_kernel<<<dim3(NTOK / TM, NE), 256, 0, stream>>>(
            x, w1, b1, w2, out, cnt, tlist, wlist);
    }
}

// Round 8
// 1164.380 us; speedup vs baseline: 3.6588x; 1.2410x over previous
//
#include <hip/hip_runtime.h>
#include <hip/hip_bf16.h>
#include <math.h>

#define NTOK 4096   // B*S
#define HD   768
#define FD   3072
#define NE   6

// ---------- vector-path (fallback) tile params ----------
#define TM   8
#define FC   128
// ---------- mfma-path params ----------
#define MT   64     // tokens per block
#define NSH  4      // F shards
#define FSH  (FD / NSH)   // 768
#define FCH  128    // F chunk
#define MAXT (8192 / MT + NE)   // 134: worst-case total tiles over all experts

typedef __attribute__((ext_vector_type(8))) short short8;
typedef __attribute__((ext_vector_type(4))) float f32x4;
#define MFMA_BF16(a, b, c) __builtin_amdgcn_mfma_f32_16x16x32_bf16(a, b, c, 0, 0, 0)

__device__ __forceinline__ float gelu_exact(float v) {
    return 0.5f * v * (1.f + erff(v * 0.70710678118654752f));
}

__device__ __forceinline__ void split_bf16(float v, short& hi, short& lo) {
    __hip_bfloat16 h = __float2bfloat16(v);
    hi = *reinterpret_cast<short*>(&h);
    float fh = __bfloat162float(h);
    __hip_bfloat16 l = __float2bfloat16(v - fh);
    lo = *reinterpret_cast<short*>(&l);
}

// ================= gating =================
__global__ __launch_bounds__(64)
void gate_kernel(const float* __restrict__ x, const float* __restrict__ gw,
                 const float* __restrict__ gb, const float* __restrict__ b2,
                 float* __restrict__ out, int* __restrict__ cnt,
                 int* __restrict__ tlist, float* __restrict__ wlist)
{
    const int n = blockIdx.x;
    const int lane = threadIdx.x;
    const float* xr = x + (size_t)n * HD;

    float p[NE] = {0.f, 0.f, 0.f, 0.f, 0.f, 0.f};
    for (int hh = lane; hh < HD; hh += 64) {
        const float xv = xr[hh];
        const float* g = gw + (size_t)hh * NE;
        #pragma unroll
        for (int e = 0; e < NE; ++e) p[e] = fmaf(xv, g[e], p[e]);
    }
    #pragma unroll
    for (int off = 32; off; off >>= 1) {
        #pragma unroll
        for (int e = 0; e < NE; ++e) p[e] += __shfl_xor(p[e], off, 64);
    }
    #pragma unroll
    for (int e = 0; e < NE; ++e) p[e] += gb[e];

    int e0 = 0; float s0 = p[0];
    #pragma unroll
    for (int e = 1; e < NE; ++e) if (p[e] > s0) { s0 = p[e]; e0 = e; }
    int e1 = -1; float s1 = -INFINITY;
    #pragma unroll
    for (int e = 0; e < NE; ++e) if (e != e0 && p[e] > s1) { s1 = p[e]; e1 = e; }

    const float ev = expf(s1 - s0);
    const float w0 = 1.f / (1.f + ev);
    const float w1 = ev / (1.f + ev);

    const float* bp0 = b2 + (size_t)e0 * HD;
    const float* bp1 = b2 + (size_t)e1 * HD;
    float* orow = out + (size_t)n * HD;
    for (int hh = lane; hh < HD; hh += 64)
        orow[hh] = fmaf(w0, bp0[hh], w1 * bp1[hh]);

    if (lane == 0) {
        int q0 = atomicAdd(&cnt[e0], 1);
        tlist[e0 * NTOK + q0] = n; wlist[e0 * NTOK + q0] = w0;
        int q1 = atomicAdd(&cnt[e1], 1);
        tlist[e1 * NTOK + q1] = n; wlist[e1 * NTOK + q1] = w1;
    }
}

// ================= tile scheduler: prefix-sum of per-expert tile counts =================
__global__ void sched_kernel(const int* __restrict__ cnt, int* __restrict__ ts)
{
    if (threadIdx.x == 0) {
        int s = 0;
        ts[0] = 0;
        for (int e = 0; e < NE; ++e) { s += (cnt[e] + MT - 1) / MT; ts[e + 1] = s; }
    }
}

// ================= prep: split x into bf16 hi/lo =================
__global__ __launch_bounds__(256)
void split_x_kernel(const float* __restrict__ x, short* __restrict__ xh, short* __restrict__ xl)
{
    const int N = NTOK * HD;
    for (int i = blockIdx.x * 256 + threadIdx.x; i < N; i += gridDim.x * 256) {
        short h, l; split_bf16(x[i], h, l);
        xh[i] = h; xl[i] = l;
    }
}

// ================= prep: pack w1 -> [e][k/8][f][8] bf16 hi/lo =================
__global__ __launch_bounds__(256)
void pack_w1_kernel(const float* __restrict__ w1, short* __restrict__ w1ph, short* __restrict__ w1pl)
{
    const int N = NE * (HD / 8) * FD;
    for (int i = blockIdx.x * 256 + threadIdx.x; i < N; i += gridDim.x * 256) {
        const int f  = i % FD;
        const int kg = (i / FD) % (HD / 8);
        const int e  = i / (FD * (HD / 8));
        const float* src = w1 + (size_t)e * HD * FD + (size_t)kg * 8 * FD + f;
        short hs[8], ls[8];
        #pragma unroll
        for (int j = 0; j < 8; ++j) split_bf16(src[(size_t)j * FD], hs[j], ls[j]);
        const size_t d = (size_t)i * 8;
        *(short8*)(w1ph + d) = *(short8*)hs;
        *(short8*)(w1pl + d) = *(short8*)ls;
    }
}

// ================= prep: pack w2 -> [e][f/8][h][8] bf16 hi/lo =================
__global__ __launch_bounds__(256)
void pack_w2_kernel(const float* __restrict__ w2, short* __restrict__ w2ph, short* __restrict__ w2pl)
{
    const int N = NE * (FD / 8) * HD;
    for (int i = blockIdx.x * 256 + threadIdx.x; i < N; i += gridDim.x * 256) {
        const int h  = i % HD;
        const int fg = (i / HD) % (FD / 8);
        const int e  = i / (HD * (FD / 8));
        const float* src = w2 + (size_t)e * FD * HD + (size_t)fg * 8 * HD + h;
        short hs[8], ls[8];
        #pragma unroll
        for (int j = 0; j < 8; ++j) split_bf16(src[(size_t)j * HD], hs[j], ls[j]);
        const size_t d = (size_t)i * 8;
        *(short8*)(w2ph + d) = *(short8*)hs;
        *(short8*)(w2pl + d) = *(short8*)ls;
    }
}

// ================= MFMA fused FFN =================
// Block = (flat tile -> (expert, 64-token tile), F-shard of 768). 512 threads = 8 waves.
// GEMM1 per 128-F chunk: C1[64][128] via 3-term split-bf16 mfma; bias+GeLU -> Hs (LDS).
// GEMM2: acc[64][768] in registers across chunks; epilogue: weighted atomicAdd.
__global__ __launch_bounds__(512, 2)
void ffn_mfma(const short* __restrict__ xh, const short* __restrict__ xl,
              const short* __restrict__ w1ph, const short* __restrict__ w1pl,
              const short* __restrict__ w2ph, const short* __restrict__ w2pl,
              const float* __restrict__ b1, float* __restrict__ out,
              const int* __restrict__ cnt, const int* __restrict__ ts,
              const int* __restrict__ tlist, const float* __restrict__ wlist)
{
    const int flat = blockIdx.x;
    if (flat >= ts[NE]) return;
    int e = 0;
    while (flat >= ts[e + 1]) ++e;          // <=6 scalar iters
    const int s = blockIdx.y;
    const int row0 = (flat - ts[e]) * MT;
    const int ce = cnt[e];
    const int nrows = min(MT, ce - row0);

    __shared__ __align__(16) short Hs_h[MT][FCH + 8];
    __shared__ __align__(16) short Hs_l[MT][FCH + 8];
    __shared__ int   toks[MT];
    __shared__ float wgts[MT];

    const int tid = threadIdx.x;
    if (tid < MT) {
        toks[tid] = tlist[e * NTOK + row0 + min(tid, nrows - 1)];
        wgts[tid] = (tid < nrows) ? wlist[e * NTOK + row0 + tid] : 0.f;
    }
    __syncthreads();

    const int lane = tid & 63;
    const int wave = tid >> 6;        // 0..7
    const int l15  = lane & 15;
    const int lk   = lane >> 4;       // 0..3
    const int wr   = wave >> 2;       // 0..1 : rows wr*32 + [0,32)
    const int wc   = wave & 3;        // 0..3 : gemm1 cols wc*32, gemm2 cols wc*192

    const int rA0 = wr * 32 + l15;
    const int rA1 = wr * 32 + 16 + l15;
    const size_t tok0 = (size_t)toks[rA0] * HD;
    const size_t tok1 = (size_t)toks[rA1] * HD;

    f32x4 acc2[2][12];
    #pragma unroll
    for (int a = 0; a < 2; ++a)
        #pragma unroll
        for (int b = 0; b < 12; ++b) acc2[a][b] = (f32x4)(0.f);

    const float* b1e = b1 + (size_t)e * FD;

    for (int ch = 0; ch < FSH / FCH; ++ch) {
        const int fbase = s * FSH + ch * FCH;

        // ---------- GEMM1: C1[64][128] ----------
        f32x4 acc1[2][2];
        #pragma unroll
        for (int a = 0; a < 2; ++a) { acc1[a][0] = (f32x4)(0.f); acc1[a][1] = (f32x4)(0.f); }

        const int fcol0 = fbase + wc * 32 + l15;
        #pragma unroll 4
        for (int ks = 0; ks < HD / 32; ++ks) {
            const int k0 = ks * 32 + lk * 8;
            const short8 ah0 = *(const short8*)(xh + tok0 + k0);
            const short8 al0 = *(const short8*)(xl + tok0 + k0);
            const short8 ah1 = *(const short8*)(xh + tok1 + k0);
            const short8 al1 = *(const short8*)(xl + tok1 + k0);
            const size_t bro = ((size_t)(e * (HD / 8) + ks * 4 + lk) * FD);
            const short8 bh0 = *(const short8*)(w1ph + (bro + fcol0) * 8);
            const short8 bl0 = *(const short8*)(w1pl + (bro + fcol0) * 8);
            const short8 bh1 = *(const short8*)(w1ph + (bro + fcol0 + 16) * 8);
            const short8 bl1 = *(const short8*)(w1pl + (bro + fcol0 + 16) * 8);
            acc1[0][0] = MFMA_BF16(ah0, bh0, acc1[0][0]);
            acc1[0][0] = MFMA_BF16(al0, bh0, acc1[0][0]);
            acc1[0][0] = MFMA_BF16(ah0, bl0, acc1[0][0]);
            acc1[0][1] = MFMA_BF16(ah0, bh1, acc1[0][1]);
            acc1[0][1] = MFMA_BF16(al0, bh1, acc1[0][1]);
            acc1[0][1] = MFMA_BF16(ah0, bl1, acc1[0][1]);
            acc1[1][0] = MFMA_BF16(ah1, bh0, acc1[1][0]);
            acc1[1][0] = MFMA_BF16(al1, bh0, acc1[1][0]);
            acc1[1][0] = MFMA_BF16(ah1, bl0, acc1[1][0]);
            acc1[1][1] = MFMA_BF16(ah1, bh1, acc1[1][1]);
            acc1[1][1] = MFMA_BF16(al1, bh1, acc1[1][1]);
            acc1[1][1] = MFMA_BF16(ah1, bl1, acc1[1][1]);
        }

        // bias + GeLU + split -> Hs
        #pragma unroll
        for (int ct = 0; ct < 2; ++ct) {
            const int flocal = wc * 32 + ct * 16 + l15;
            const float bias = b1e[fbase + flocal];
            #pragma unroll
            for (int rt = 0; rt < 2; ++rt) {
                #pragma unroll
                for (int j = 0; j < 4; ++j) {
                    const float v = gelu_exact(acc1[rt][ct][j] + bias);
                    short h, l; split_bf16(v, h, l);
                    const int r = wr * 32 + rt * 16 + lk * 4 + j;
                    Hs_h[r][flocal] = h;
                    Hs_l[r][flocal] = l;
                }
            }
        }
        __syncthreads();

        // ---------- GEMM2: acc2 += H[64][128] @ w2[128][768-slice] ----------
        #pragma unroll
        for (int ks = 0; ks < FCH / 32; ++ks) {
            const int k0 = ks * 32 + lk * 8;
            const short8 ah0 = *(const short8*)&Hs_h[wr * 32 + l15][k0];
            const short8 al0 = *(const short8*)&Hs_l[wr * 32 + l15][k0];
            const short8 ah1 = *(const short8*)&Hs_h[wr * 32 + 16 + l15][k0];
            const short8 al1 = *(const short8*)&Hs_l[wr * 32 + 16 + l15][k0];
            const size_t bro = (size_t)(e * (FD / 8) + ((fbase + ks * 32) >> 3) + lk) * HD;
            #pragma unroll
            for (int ct = 0; ct < 12; ++ct) {
                const int h = wc * 192 + ct * 16 + l15;
                const short8 bh = *(const short8*)(w2ph + (bro + h) * 8);
                const short8 bl = *(const short8*)(w2pl + (bro + h) * 8);
                acc2[0][ct] = MFMA_BF16(ah0, bh, acc2[0][ct]);
                acc2[0][ct] = MFMA_BF16(al0, bh, acc2[0][ct]);
                acc2[0][ct] = MFMA_BF16(ah0, bl, acc2[0][ct]);
                acc2[1][ct] = MFMA_BF16(ah1, bh, acc2[1][ct]);
                acc2[1][ct] = MFMA_BF16(al1, bh, acc2[1][ct]);
                acc2[1][ct] = MFMA_BF16(ah1, bl, acc2[1][ct]);
            }
        }
        __syncthreads();
    }

    // ---------- epilogue ----------
    #pragma unroll
    for (int rt = 0; rt < 2; ++rt) {
        #pragma unroll
        for (int j = 0; j < 4; ++j) {
            const int r = wr * 32 + rt * 16 + lk * 4 + j;
            if (r < nrows) {
                const float wg = wgts[r];
                float* orow = out + (size_t)toks[r] * HD;
                #pragma unroll
                for (int ct = 0; ct < 12; ++ct)
                    atomicAdd(&orow[wc * 192 + ct * 16 + l15], wg * acc2[rt][ct][j]);
            }
        }
    }
}

// ================= vector fallback FFN =================
__global__ __launch_bounds__(256, 4)
void ffn_kernel(const float* __restrict__ x, const float* __restrict__ w1,
                const float* __restrict__ b1, const float* __restrict__ w2,
                float* __restrict__ out, const int* __restrict__ cnt,
                const int* __restrict__ tlist, const float* __restrict__ wlist)
{
    const int e = blockIdx.y;
    const int ce = cnt[e];
    const int row0 = blockIdx.x * TM;
    if (row0 >= ce) return;
    const int nrows = min(TM, ce - row0);

    __shared__ float Xs[TM][HD + 4];
    __shared__ float Hs[2][TM][FC + 4];
    __shared__ int   toks[TM];
    __shared__ float wgts[TM];

    const int tid = threadIdx.x;
    if (tid < TM) {
        const int idx = row0 + min(tid, nrows - 1);
        toks[tid] = tlist[e * NTOK + idx];
        wgts[tid] = (tid < nrows) ? wlist[e * NTOK + row0 + tid] : 0.f;
    }
    __syncthreads();

    for (int i = tid; i < TM * (HD / 4); i += 256) {
        const int m = i / (HD / 4), c = i % (HD / 4);
        ((float4*)&Xs[m][0])[c] = ((const float4*)(x + (size_t)toks[m] * HD))[c];
    }

    float acc[TM * 3];
    #pragma unroll
    for (int i = 0; i < TM * 3; ++i) acc[i] = 0.f;

    const float* w1e = w1 + (size_t)e * HD * FD;
    const float* w2e = w2 + (size_t)e * FD * HD;
    const float* b1e = b1 + (size_t)e * FD;

    const int fc0 = (tid & 31) * 4;
    const int mg  = tid >> 5;

    __syncthreads();

    for (int c = 0; c < FD / FC; ++c) {
        const int f0 = c * FC;
        const int buf = c & 1;
        float d0 = 0.f, d1 = 0.f, d2 = 0.f, d3 = 0.f;
        const float* wcp = w1e + f0 + fc0;
        #pragma unroll 2
        for (int hh = 0; hh < HD; hh += 4) {
            const float4 xv = *(const float4*)&Xs[mg][hh];
            const float4 a0 = *(const float4*)(wcp + (size_t)(hh + 0) * FD);
            const float4 a1 = *(const float4*)(wcp + (size_t)(hh + 1) * FD);
            const float4 a2 = *(const float4*)(wcp + (size_t)(hh + 2) * FD);
            const float4 a3 = *(const float4*)(wcp + (size_t)(hh + 3) * FD);
            d0 = fmaf(xv.x, a0.x, d0); d0 = fmaf(xv.y, a1.x, d0);
            d0 = fmaf(xv.z, a2.x, d0); d0 = fmaf(xv.w, a3.x, d0);
            d1 = fmaf(xv.x, a0.y, d1); d1 = fmaf(xv.y, a1.y, d1);
            d1 = fmaf(xv.z, a2.y, d1); d1 = fmaf(xv.w, a3.y, d1);
            d2 = fmaf(xv.x, a0.z, d2); d2 = fmaf(xv.y, a1.z, d2);
            d2 = fmaf(xv.z, a2.z, d2); d2 = fmaf(xv.w, a3.z, d2);
            d3 = fmaf(xv.x, a0.w, d3); d3 = fmaf(xv.y, a1.w, d3);
            d3 = fmaf(xv.z, a2.w, d3); d3 = fmaf(xv.w, a3.w, d3);
        }
        const float4 bv = *(const float4*)&b1e[f0 + fc0];
        float4 hv;
        hv.x = gelu_exact(d0 + bv.x);
        hv.y = gelu_exact(d1 + bv.y);
        hv.z = gelu_exact(d2 + bv.z);
        hv.w = gelu_exact(d3 + bv.w);
        *(float4*)&Hs[buf][mg][fc0] = hv;
        __syncthreads();

        for (int f = 0; f < FC; f += 4) {
            const float4 h0 = *(const float4*)&Hs[buf][0][f];
            const float4 h1 = *(const float4*)&Hs[buf][1][f];
            const float4 h2 = *(const float4*)&Hs[buf][2][f];
            const float4 h3 = *(const float4*)&Hs[buf][3][f];
            const float4 h4 = *(const float4*)&Hs[buf][4][f];
            const float4 h5 = *(const float4*)&Hs[buf][5][f];
            const float4 h6 = *(const float4*)&Hs[buf][6][f];
            const float4 h7 = *(const float4*)&Hs[buf][7][f];
            #pragma unroll
            for (int j = 0; j < 4; ++j) {
                const float* wr = w2e + (size_t)(f0 + f + j) * HD + tid;
                const float wa = wr[0], wb = wr[256], wcv = wr[512];
                const float m0 = ((const float*)&h0)[j];
                const float m1 = ((const float*)&h1)[j];
                const float m2 = ((const float*)&h2)[j];
                const float m3 = ((const float*)&h3)[j];
                const float m4 = ((const float*)&h4)[j];
                const float m5 = ((const float*)&h5)[j];
                const float m6 = ((const float*)&h6)[j];
                const float m7 = ((const float*)&h7)[j];
                acc[0*3+0] = fmaf(m0, wa, acc[0*3+0]); acc[0*3+1] = fmaf(m0, wb, acc[0*3+1]); acc[0*3+2] = fmaf(m0, wcv, acc[0*3+2]);
                acc[1*3+0] = fmaf(m1, wa, acc[1*3+0]); acc[1*3+1] = fmaf(m1, wb, acc[1*3+1]); acc[1*3+2] = fmaf(m1, wcv, acc[1*3+2]);
                acc[2*3+0] = fmaf(m2, wa, acc[2*3+0]); acc[2*3+1] = fmaf(m2, wb, acc[2*3+1]); acc[2*3+2] = fmaf(m2, wcv, acc[2*3+2]);
                acc[3*3+0] = fmaf(m3, wa, acc[3*3+0]); acc[3*3+1] = fmaf(m3, wb, acc[3*3+1]); acc[3*3+2] = fmaf(m3, wcv, acc[3*3+2]);
                acc[4*3+0] = fmaf(m4, wa, acc[4*3+0]); acc[4*3+1] = fmaf(m4, wb, acc[4*3+1]); acc[4*3+2] = fmaf(m4, wcv, acc[4*3+2]);
                acc[5*3+0] = fmaf(m5, wa, acc[5*3+0]); acc[5*3+1] = fmaf(m5, wb, acc[5*3+1]); acc[5*3+2] = fmaf(m5, wcv, acc[5*3+2]);
                acc[6*3+0] = fmaf(m6, wa, acc[6*3+0]); acc[6*3+1] = fmaf(m6, wb, acc[6*3+1]); acc[6*3+2] = fmaf(m6, wcv, acc[6*3+2]);
                acc[7*3+0] = fmaf(m7, wa, acc[7*3+0]); acc[7*3+1] = fmaf(m7, wb, acc[7*3+1]); acc[7*3+2] = fmaf(m7, wcv, acc[7*3+2]);
            }
        }
    }

    #pragma unroll
    for (int m = 0; m < TM; ++m) {
        if (m < nrows) {
            const float wg = wgts[m];
            float* orow = out + (size_t)toks[m] * HD;
            atomicAdd(&orow[tid],        wg * acc[m * 3 + 0]);
            atomicAdd(&orow[tid + 256],  wg * acc[m * 3 + 1]);
            atomicAdd(&orow[tid + 512],  wg * acc[m * 3 + 2]);
        }
    }
}

extern "C" void kernel_launch(void* const* d_in, const int* in_sizes, int n_in,
                              void* d_out, int out_size, void* d_ws, size_t ws_size,
                              hipStream_t stream) {
    const float* x  = (const float*)d_in[0];
    const float* gw = (const float*)d_in[1];
    const float* gb = (const float*)d_in[2];
    const float* w1 = (const float*)d_in[3];
    const float* b1 = (const float*)d_in[4];
    const float* w2 = (const float*)d_in[5];
    const float* b2 = (const float*)d_in[6];
    float* out = (float*)d_out;

    char* ws = (char*)d_ws;
    int*   cnt   = (int*)ws;                 // 6 ints at [0,24)
    int*   tsp   = (int*)(ws + 32);          // 7 ints at [32,60)
    int*   tlist = (int*)(ws + 64);
    float* wlist = (float*)(ws + 64 + (size_t)NE * NTOK * 4);

    const size_t base   = 196864;                 // 256-aligned end of lists
    const size_t sz_x   = (size_t)NTOK * HD * 2;  // bf16
    const size_t sz_w1  = (size_t)NE * HD * FD * 2;
    const size_t sz_w2  = (size_t)NE * FD * HD * 2;
    const size_t REQ    = base + 2 * sz_x + 2 * sz_w1 + 2 * sz_w2;

    hipMemsetAsync(cnt, 0, 64, stream);
    gate_kernel<<<NTOK, 64, 0, stream>>>(x, gw, gb, b2, out, cnt, tlist, wlist);

    if (ws_size >= REQ) {
        short* xh   = (short*)(ws + base);
        short* xl   = (short*)(ws + base + sz_x);
        short* w1ph = (short*)(ws + base + 2 * sz_x);
        short* w1pl = (short*)(ws + base + 2 * sz_x + sz_w1);
        short* w2ph = (short*)(ws + base + 2 * sz_x + 2 * sz_w1);
        short* w2pl = (short*)(ws + base + 2 * sz_x + 2 * sz_w1 + sz_w2);

        sched_kernel<<<1, 64, 0, stream>>>(cnt, tsp);
        split_x_kernel<<<2048, 256, 0, stream>>>(x, xh, xl);
        pack_w1_kernel<<<2048, 256, 0, stream>>>(w1, w1ph, w1pl);
        pack_w2_kernel<<<2048, 256, 0, stream>>>(w2, w2ph, w2pl);
        ffn_mfma<<<dim3(MAXT, NSH, 1), 512, 0, stream>>>(
            xh, xl, w1ph, w1pl, w2ph, w2pl, b1, out, cnt, tsp, tlist, wlist);
    } else {
        ffn_kernel<<<dim3(NTOK / TM, NE), 256, 0, stream>>>(
            x, w1, b1, w2, out, cnt, tlist, wlist);
    }
}